// Round 1
// baseline (419.792 us; speedup 1.0000x reference)
//
#include <hip/hip_runtime.h>

#define N_COLS 8192

// Kernel 1: single block. Reduce max over x[0:8192], then build the spike
// mask: spikes[i] = (int(floor(x[i]/maxv * 255)) == t) ? 1.0f : 0.0f.
// Exact IEEE div then mul then floorf -> bit-matches the numpy reference.
__global__ __launch_bounds__(1024) void spike_kernel(const float* __restrict__ x,
                                                     const int* __restrict__ t_ptr,
                                                     float* __restrict__ spikes) {
    __shared__ float smax[16];
    __shared__ float s_maxv;
    const int tid = threadIdx.x;  // 0..1023

    float vals[8];
    float m = -1e30f;
#pragma unroll
    for (int j = 0; j < 8; ++j) {
        vals[j] = x[tid + j * 1024];
        m = fmaxf(m, vals[j]);
    }
    // wave(64) butterfly-ish reduce via shfl_down
#pragma unroll
    for (int off = 32; off > 0; off >>= 1)
        m = fmaxf(m, __shfl_down(m, off, 64));
    if ((tid & 63) == 0) smax[tid >> 6] = m;
    __syncthreads();
    if (tid < 16) {
        float mm = smax[tid];
#pragma unroll
        for (int off = 8; off > 0; off >>= 1)
            mm = fmaxf(mm, __shfl_down(mm, off, 16));
        if (tid == 0) s_maxv = mm;
    }
    __syncthreads();

    const float maxv = s_maxv;
    const int t = *t_ptr;
#pragma unroll
    for (int j = 0; j < 8; ++j) {
        const int q = (int)floorf((vals[j] / maxv) * 255.0f);
        spikes[tid + j * 1024] = (q == t) ? 1.0f : 0.0f;
    }
}

// Kernel 2: out[i] = w[i] * spikes[i % 8192], float4-vectorized.
// ~99.6% of spike values are 0, so skip the weight load when the 4-wide
// spike group is all zero -> HBM read traffic drops from 256 MB to ~tens of MB.
__global__ __launch_bounds__(256) void mul_kernel(const float4* __restrict__ w,
                                                  const float* __restrict__ spikes,
                                                  float4* __restrict__ out) {
    const unsigned int i = blockIdx.x * blockDim.x + threadIdx.x;  // float4 index
    const unsigned int col = (i * 4u) & (N_COLS - 1);              // multiple of 4
    const float4 s = *(const float4*)(spikes + col);
    float4 o;
    if (s.x == 0.0f && s.y == 0.0f && s.z == 0.0f && s.w == 0.0f) {
        o = make_float4(0.0f, 0.0f, 0.0f, 0.0f);
    } else {
        const float4 wv = w[i];
        o = make_float4(wv.x * s.x, wv.y * s.y, wv.z * s.z, wv.w * s.w);
    }
    out[i] = o;
}

extern "C" void kernel_launch(void* const* d_in, const int* in_sizes, int n_in,
                              void* d_out, int out_size, void* d_ws, size_t ws_size,
                              hipStream_t stream) {
    const float* x = (const float*)d_in[0];          // [1, 8192] fp32
    const float4* w = (const float4*)d_in[1];        // [8192, 8192] fp32
    const int* t = (const int*)d_in[2];              // scalar int
    float* out = (float*)d_out;                      // [8192, 8192] fp32
    float* spikes = (float*)d_ws;                    // 8192 floats scratch

    spike_kernel<<<1, 1024, 0, stream>>>(x, t, spikes);

    const int n4 = out_size / 4;                     // 16,777,216 float4s
    mul_kernel<<<n4 / 256, 256, 0, stream>>>(w, spikes, (float4*)out);
}

// Round 2
// 413.955 us; speedup vs baseline: 1.0141x; 1.0141x over previous
//
#include <hip/hip_runtime.h>

#define N_COLS 8192
#define LOG2_COLS 13

// Kernel 1: single block. Max-reduce over x[0:8192], build spike mask, and
// COMPACT the spike column indices into d_ws: meta[0]=count, meta[1..]=cols.
// Exact IEEE div -> mul -> floorf bit-matches the numpy reference.
__global__ __launch_bounds__(1024) void spike_kernel(const float* __restrict__ x,
                                                     const int* __restrict__ t_ptr,
                                                     int* __restrict__ meta) {
    __shared__ float smax[16];
    __shared__ float s_maxv;
    __shared__ int s_count;
    const int tid = threadIdx.x;  // 0..1023

    if (tid == 0) s_count = 0;

    float vals[8];
    float m = -1e30f;
#pragma unroll
    for (int j = 0; j < 8; ++j) {
        vals[j] = x[tid + j * 1024];
        m = fmaxf(m, vals[j]);
    }
#pragma unroll
    for (int off = 32; off > 0; off >>= 1)
        m = fmaxf(m, __shfl_down(m, off, 64));
    if ((tid & 63) == 0) smax[tid >> 6] = m;
    __syncthreads();
    if (tid < 16) {
        float mm = smax[tid];
#pragma unroll
        for (int off = 8; off > 0; off >>= 1)
            mm = fmaxf(mm, __shfl_down(mm, off, 16));
        if (tid == 0) s_maxv = mm;
    }
    __syncthreads();

    const float maxv = s_maxv;
    const int t = *t_ptr;
#pragma unroll
    for (int j = 0; j < 8; ++j) {
        const int q = (int)floorf((vals[j] / maxv) * 255.0f);
        if (q == t) {
            const int slot = atomicAdd(&s_count, 1);
            meta[1 + slot] = tid + j * 1024;   // column index
        }
    }
    __syncthreads();
    if (tid == 0) meta[0] = s_count;
}

// Kernel 2: after d_out has been memset to zero, copy weight[:,c] -> out[:,c]
// for each compacted spike column c. Grid-stride; handles any count 0..8192.
__global__ __launch_bounds__(256) void scatter_kernel(const float* __restrict__ w,
                                                      const int* __restrict__ meta,
                                                      float* __restrict__ out) {
    const int count = meta[0];
    const int* cols = meta + 1;
    const long total = (long)count << LOG2_COLS;          // count * 8192 rows
    const long stride = (long)gridDim.x * blockDim.x;
    for (long idx = (long)blockIdx.x * blockDim.x + threadIdx.x; idx < total;
         idx += stride) {
        const int k = (int)(idx >> LOG2_COLS);            // spike-list index
        const int r = (int)(idx & (N_COLS - 1));          // row
        const long off = ((long)r << LOG2_COLS) + cols[k];
        out[off] = w[off];                                 // spike==1.0 exactly
    }
}

extern "C" void kernel_launch(void* const* d_in, const int* in_sizes, int n_in,
                              void* d_out, int out_size, void* d_ws, size_t ws_size,
                              hipStream_t stream) {
    const float* x = (const float*)d_in[0];   // [1, 8192] fp32
    const float* w = (const float*)d_in[1];   // [8192, 8192] fp32
    const int* t = (const int*)d_in[2];       // scalar int
    float* out = (float*)d_out;               // [8192, 8192] fp32
    int* meta = (int*)d_ws;                   // [0]=count, [1..8192]=cols

    // 1) Build compacted spike-column list (tiny, 1 block).
    spike_kernel<<<1, 1024, 0, stream>>>(x, t, meta);

    // 2) Zero the full output via the fast rocclr fill path (~6.4 TB/s).
    hipMemsetAsync(out, 0, (size_t)out_size * sizeof(float), stream);

    // 3) Overwrite only the spike columns with weight values.
    scatter_kernel<<<2048, 256, 0, stream>>>(w, meta, out);
}